// Round 2
// baseline (11132.343 us; speedup 1.0000x reference)
//
#include <hip/hip_runtime.h>
#include <cstdint>

#define H 256

typedef unsigned short u16;
typedef __attribute__((ext_vector_type(8))) short short8;
typedef __attribute__((ext_vector_type(4))) float f32x4;

__device__ __forceinline__ float bf2f(u16 u) {
  return __uint_as_float(((unsigned)u) << 16);
}
__device__ __forceinline__ u16 f2bf(float f) {
  unsigned u = __float_as_uint(f);
  u = (u + 0x7FFF + ((u >> 16) & 1)) >> 16;   // RNE
  return (u16)u;
}
__device__ __forceinline__ void async16(const void* g, void* l) {
  __builtin_amdgcn_global_load_lds((const __attribute__((address_space(1))) void*)g,
                                   (__attribute__((address_space(3))) void*)l, 16, 0, 0);
}

// ---- fp32 -> bf16 converters (MFMA operand prep) ----
__global__ __launch_bounds__(256) void cvt_bf16(
    const float* __restrict__ src, u16* __restrict__ dst, int total)
{
  int i = (blockIdx.x * 256 + threadIdx.x) * 4;
  if (i >= total) return;
  float4 x = *(const float4*)(src + i);
  *(ushort4*)(dst + i) = make_ushort4(f2bf(x.x), f2bf(x.y), f2bf(x.z), f2bf(x.w));
}

// 6 tensors of H*H fp32 -> bf16 slots; grid (H*H/1024, 6)
__global__ __launch_bounds__(256) void cvt_weights(
    const float* w0, const float* w1, const float* w2, const float* w3,
    const float* w4, const float* w5, u16* __restrict__ dst)
{
  const float* srcs[6] = {w0, w1, w2, w3, w4, w5};
  const float* s = srcs[blockIdx.y];
  int i = (blockIdx.x * 256 + threadIdx.x) * 4;
  float4 x = *(const float4*)(s + i);
  *(ushort4*)(dst + blockIdx.y * (H * H) + i) =
      make_ushort4(f2bf(x.x), f2bf(x.y), f2bf(x.z), f2bf(x.w));
}

// C[M,256] = A[M,256] @ W[256,256]^T   (bf16 operands, fp32 accum)
// MODE 0: store C as bf16
// MODE 1: colsum[n] += sum_m tanh(C[m][n] + bias[n])   (C never stored)
template <int MODE>
__global__ __launch_bounds__(256) void gemm_bt(
    const u16* __restrict__ A, const u16* __restrict__ W,
    u16* __restrict__ C, const float* __restrict__ bias,
    float* __restrict__ colsum, int M)
{
  __shared__ u16 As[128 * 64];   // 16 KB
  __shared__ u16 Bs[128 * 64];   // 16 KB
  const int tid  = threadIdx.x;
  const int lane = tid & 63;
  const int wave = tid >> 6;
  const int quad = lane >> 4;
  const int l15  = lane & 15;
  const int m0 = blockIdx.x * 128;
  const int n0 = blockIdx.y * 128;
  const int wr = (wave & 1) * 64;
  const int wc = (wave >> 1) * 64;

  f32x4 acc[4][4] = {};

  for (int k0 = 0; k0 < H; k0 += 64) {
    #pragma unroll
    for (int r = 0; r < 4; ++r) {
      int chunk = r * 256 + tid;       // 16B chunk id, 8 chunks per 64-elem row
      int row = chunk >> 3;
      int col = (chunk & 7) * 8;
      int gm = m0 + row; if (gm >= M) gm = M - 1;     // clamp (stores/sums guarded)
      u16* lbase = As + (r * 256 + wave * 64) * 8;    // wave-uniform LDS base
      async16(A + gm * H + k0 + col, lbase);
      u16* lbase2 = Bs + (r * 256 + wave * 64) * 8;
      async16(W + (n0 + row) * H + k0 + col, lbase2);
    }
    __syncthreads();
    #pragma unroll
    for (int kk = 0; kk < 64; kk += 32) {
      short8 af[4], bf[4];
      #pragma unroll
      for (int i = 0; i < 4; ++i) {
        af[i] = *(const short8*)(As + (wr + i * 16 + l15) * 64 + kk + quad * 8);
        bf[i] = *(const short8*)(Bs + (wc + i * 16 + l15) * 64 + kk + quad * 8);
      }
      #pragma unroll
      for (int mi = 0; mi < 4; ++mi)
        #pragma unroll
        for (int ni = 0; ni < 4; ++ni)
          acc[mi][ni] = __builtin_amdgcn_mfma_f32_16x16x32_bf16(af[mi], bf[ni], acc[mi][ni], 0, 0, 0);
    }
    __syncthreads();
  }

  if (MODE == 0) {
    #pragma unroll
    for (int mi = 0; mi < 4; ++mi)
      #pragma unroll
      for (int ni = 0; ni < 4; ++ni) {
        int n = n0 + wc + ni * 16 + l15;
        #pragma unroll
        for (int j = 0; j < 4; ++j) {
          int m = m0 + wr + mi * 16 + quad * 4 + j;   // C/D: col=lane&15, row=quad*4+reg
          if (m < M) C[m * H + n] = f2bf(acc[mi][ni][j]);
        }
      }
  } else {
    #pragma unroll
    for (int ni = 0; ni < 4; ++ni) {
      int n = n0 + wc + ni * 16 + l15;
      float bv = bias[n];
      float s = 0.f;
      #pragma unroll
      for (int mi = 0; mi < 4; ++mi)
        #pragma unroll
        for (int j = 0; j < 4; ++j) {
          int m = m0 + wr + mi * 16 + quad * 4 + j;
          if (m < M) {
            float x = acc[mi][ni][j] + bv;
            s += 1.f - 2.f / (__expf(2.f * x) + 1.f);  // tanh, overflow-safe
          }
        }
      s += __shfl_xor(s, 16);
      s += __shfl_xor(s, 32);
      if (lane < 16) unsafeAtomicAdd(&colsum[n], s);
    }
  }
}

// one wave per edge: accum[dst] += val * fts[src]
__global__ __launch_bounds__(256) void spmm_atomic(
    const u16* __restrict__ fts, const int* __restrict__ idx,
    const float* __restrict__ val, float* __restrict__ accum, int E)
{
  int gw = (int)((blockIdx.x * 256 + threadIdx.x) >> 6);
  if (gw >= E) return;
  int lane = threadIdx.x & 63;
  int dst = idx[gw];        // idx[0][e]
  int src = idx[E + gw];    // idx[1][e]
  float v = val[gw];
  ushort4 r = *(const ushort4*)(fts + src * H + lane * 4);
  float* op = accum + dst * H + lane * 4;
  unsafeAtomicAdd(op + 0, v * bf2f(r.x));
  unsafeAtomicAdd(op + 1, v * bf2f(r.y));
  unsafeAtomicAdd(op + 2, v * bf2f(r.z));
  unsafeAtomicAdd(op + 3, v * bf2f(r.w));
}

__global__ __launch_bounds__(256) void bias_prelu(
    const float* __restrict__ acc, const float* __restrict__ b,
    const float* __restrict__ a, u16* __restrict__ e, int total)
{
  int i = (blockIdx.x * 256 + threadIdx.x) * 4;
  if (i >= total) return;
  float alpha = a[0];
  float4 x = *(const float4*)(acc + i);
  int h = i & (H - 1);
  float r0 = x.x + b[h];
  float r1 = x.y + b[h + 1];
  float r2 = x.z + b[h + 2];
  float r3 = x.w + b[h + 3];
  r0 = r0 > 0.f ? r0 : alpha * r0;
  r1 = r1 > 0.f ? r1 : alpha * r1;
  r2 = r2 > 0.f ? r2 : alpha * r2;
  r3 = r3 > 0.f ? r3 : alpha * r3;
  *(ushort4*)(e + i) = make_ushort4(f2bf(r0), f2bf(r1), f2bf(r2), f2bf(r3));
}

__global__ __launch_bounds__(256) void compute_beta(
    const float* __restrict__ sp, const float* __restrict__ att,
    float invN, float* __restrict__ beta)
{
  __shared__ float red0[4], red1[4];
  int t = threadIdx.x;
  float a = att[t];
  float s0 = sp[t] * invN * a;
  float s1 = sp[H + t] * invN * a;
  #pragma unroll
  for (int off = 32; off > 0; off >>= 1) {
    s0 += __shfl_down(s0, off);
    s1 += __shfl_down(s1, off);
  }
  int lane = t & 63, w = t >> 6;
  if (lane == 0) { red0[w] = s0; red1[w] = s1; }
  __syncthreads();
  if (t == 0) {
    float a0 = red0[0] + red0[1] + red0[2] + red0[3];
    float a1 = red1[0] + red1[1] + red1[2] + red1[3];
    float mx = fmaxf(a0, a1);
    float e0v = __expf(a0 - mx), e1v = __expf(a1 - mx);
    float inv = 1.f / (e0v + e1v);
    beta[0] = e0v * inv;
    beta[1] = e1v * inv;
  }
}

__global__ __launch_bounds__(256) void fuse_out(
    const u16* __restrict__ e0, const u16* __restrict__ e1,
    const float* __restrict__ beta, float* __restrict__ out, int total)
{
  int i = (blockIdx.x * 256 + threadIdx.x) * 4;
  if (i >= total) return;
  float b0 = beta[0], b1 = beta[1];
  ushort4 u0 = *(const ushort4*)(e0 + i);
  ushort4 u1 = *(const ushort4*)(e1 + i);
  float4 o;
  o.x = b0 * bf2f(u0.x) + b1 * bf2f(u1.x);
  o.y = b0 * bf2f(u0.y) + b1 * bf2f(u1.y);
  o.z = b0 * bf2f(u0.z) + b1 * bf2f(u1.z);
  o.w = b0 * bf2f(u0.w) + b1 * bf2f(u1.w);
  *(float4*)(out + i) = o;
}

extern "C" void kernel_launch(void* const* d_in, const int* in_sizes, int n_in,
                              void* d_out, int out_size, void* d_ws, size_t ws_size,
                              hipStream_t stream)
{
  const float* h_in[2] = {(const float*)d_in[0], (const float*)d_in[1]};
  const int N = in_sizes[0] / H;      // 50000
  const int E = in_sizes[3];          // 800000
  const int* idx[4]; const float* val[4];
  for (int i = 0; i < 4; ++i) {
    idx[i] = (const int*)d_in[2 + 2 * i];
    val[i] = (const float*)d_in[3 + 2 * i];
  }
  const float *W[4], *bia[4], *alp[4];
  for (int i = 0; i < 4; ++i) {
    W[i]   = (const float*)d_in[10 + 3 * i];
    bia[i] = (const float*)d_in[11 + 3 * i];
    alp[i] = (const float*)d_in[12 + 3 * i];
  }
  const float *fcW[2], *fcb[2], *att[2];
  for (int s = 0; s < 2; ++s) {
    fcW[s] = (const float*)d_in[22 + 3 * s];
    fcb[s] = (const float*)d_in[23 + 3 * s];
    att[s] = (const float*)d_in[24 + 3 * s];
  }

  const size_t NH = (size_t)N * H;
  char* p = (char*)d_ws;
  float* accum = (float*)p; p += NH * 4;        // 51.2 MB
  u16* fts = (u16*)p;       p += NH * 2;        // 25.6 MB (aliases e1)
  u16* e0b = (u16*)p;       p += NH * 2;        // 25.6 MB
  u16* hbf = (u16*)p;       p += NH * 2;        // 25.6 MB
  u16* Wbf = (u16*)p;       p += 6 * H * H * 2; // 768 KB
  float* sp = (float*)p;    p += 2 * H * 4;
  float* beta = (float*)p;
  u16* e1b = fts;           // fts is dead by the time e1 is written

  const int gx = (N + 127) / 128;
  dim3 ggrid(gx, 2);
  const int tot = (int)NH;
  const int ew_blocks = (E + 3) / 4;          // 4 edges (waves) per block
  const int el_blocks = tot / 4 / 256;        // tot divisible by 1024

  // convert the 6 weight matrices once: W[0..3] -> slots 0..3, fcW[0..1] -> 4,5
  dim3 wgrid(H * H / 1024, 6);
  cvt_weights<<<wgrid, 256, 0, stream>>>(W[0], W[1], W[2], W[3], fcW[0], fcW[1], Wbf);

  for (int s = 0; s < 2; ++s) {
    float* outz = (float*)d_out + (size_t)s * NH;
    cvt_bf16<<<el_blocks, 256, 0, stream>>>(h_in[s], hbf, tot);
    for (int m = 0; m < 2; ++m) {
      int pi = s * 2 + m;
      gemm_bt<0><<<ggrid, 256, 0, stream>>>(hbf, Wbf + (size_t)pi * H * H, fts,
                                            nullptr, nullptr, N);
      hipMemsetAsync(accum, 0, NH * 4, stream);
      spmm_atomic<<<ew_blocks, 256, 0, stream>>>(fts, idx[pi], val[pi], accum, E);
      bias_prelu<<<el_blocks, 256, 0, stream>>>(accum, bia[pi], alp[pi],
                                                m == 0 ? e0b : e1b, tot);
    }
    hipMemsetAsync(sp, 0, 2 * H * 4, stream);
    gemm_bt<1><<<ggrid, 256, 0, stream>>>(e0b, Wbf + (size_t)(4 + s) * H * H,
                                          nullptr, fcb[s], sp, N);
    gemm_bt<1><<<ggrid, 256, 0, stream>>>(e1b, Wbf + (size_t)(4 + s) * H * H,
                                          nullptr, fcb[s], sp + H, N);
    compute_beta<<<1, 256, 0, stream>>>(sp, att[s], 1.0f / (float)N, beta);
    fuse_out<<<el_blocks, 256, 0, stream>>>(e0b, e1b, beta, outz, tot);
  }
}

// Round 3
// 1133.855 us; speedup vs baseline: 9.8181x; 9.8181x over previous
//
#include <hip/hip_runtime.h>
#include <cstdint>

#define H 256

typedef unsigned short u16;
typedef __attribute__((ext_vector_type(8))) short short8;
typedef __attribute__((ext_vector_type(4))) float f32x4;

__device__ __forceinline__ float bf2f(u16 u) {
  return __uint_as_float(((unsigned)u) << 16);
}
__device__ __forceinline__ u16 f2bf(float f) {
  unsigned u = __float_as_uint(f);
  u = (u + 0x7FFF + ((u >> 16) & 1)) >> 16;   // RNE
  return (u16)u;
}
__device__ __forceinline__ void async16(const void* g, void* l) {
  __builtin_amdgcn_global_load_lds((const __attribute__((address_space(1))) void*)g,
                                   (__attribute__((address_space(3))) void*)l, 16, 0, 0);
}

// ---- fp32 -> bf16 converters ----
__global__ __launch_bounds__(256) void cvt_bf16(
    const float* __restrict__ src, u16* __restrict__ dst, int total)
{
  int i = (blockIdx.x * 256 + threadIdx.x) * 4;
  if (i >= total) return;
  float4 x = *(const float4*)(src + i);
  *(ushort4*)(dst + i) = make_ushort4(f2bf(x.x), f2bf(x.y), f2bf(x.z), f2bf(x.w));
}

__global__ __launch_bounds__(256) void cvt_weights(
    const float* w0, const float* w1, const float* w2, const float* w3,
    const float* w4, const float* w5, u16* __restrict__ dst)
{
  const float* srcs[6] = {w0, w1, w2, w3, w4, w5};
  const float* s = srcs[blockIdx.y];
  int i = (blockIdx.x * 256 + threadIdx.x) * 4;
  float4 x = *(const float4*)(s + i);
  *(ushort4*)(dst + blockIdx.y * (H * H) + i) =
      make_ushort4(f2bf(x.x), f2bf(x.y), f2bf(x.z), f2bf(x.w));
}

// ================= CSR build (batched over 2 metapaths via blockIdx.y) ========

__global__ __launch_bounds__(256) void hist_edges(
    const int* __restrict__ i0, const int* __restrict__ i1,
    int* __restrict__ deg, int N, int E)
{
  int mp = blockIdx.y;
  const int* idx = mp ? i1 : i0;
  int e = blockIdx.x * 256 + threadIdx.x;
  if (e < E) atomicAdd(&deg[mp * N + idx[e]], 1);
}

__device__ __forceinline__ int block_incl_scan(int v) {
  __shared__ int wsum[4];
  int tid = threadIdx.x, lane = tid & 63, w = tid >> 6;
  int x = v;
  #pragma unroll
  for (int off = 1; off < 64; off <<= 1) {
    int n = __shfl_up(x, off);
    if (lane >= off) x += n;
  }
  if (lane == 63) wsum[w] = x;
  __syncthreads();
  int add = 0;
  #pragma unroll
  for (int i = 0; i < 4; ++i) add += (i < w) ? wsum[i] : 0;
  return x + add;
}

__global__ __launch_bounds__(256) void scan_partial(
    const int* __restrict__ deg, int* __restrict__ bsum, int N, int nb)
{
  int mp = blockIdx.y;
  int i = blockIdx.x * 256 + threadIdx.x;
  int v = (i < N) ? deg[mp * N + i] : 0;
  #pragma unroll
  for (int off = 32; off; off >>= 1) v += __shfl_down(v, off);
  __shared__ int ws2[4];
  int lane = threadIdx.x & 63, w = threadIdx.x >> 6;
  if (lane == 0) ws2[w] = v;
  __syncthreads();
  if (threadIdx.x == 0)
    bsum[mp * nb + blockIdx.x] = ws2[0] + ws2[1] + ws2[2] + ws2[3];
}

// nb <= 256 required (N<=65536): scans block sums in place -> exclusive offsets
__global__ __launch_bounds__(256) void scan_blocks(
    int* __restrict__ bsum, int* __restrict__ rowptr, int N, int nb, int E)
{
  int mp = blockIdx.y;
  int t = threadIdx.x;
  int v = (t < nb) ? bsum[mp * nb + t] : 0;
  int incl = block_incl_scan(v);
  if (t < nb) bsum[mp * nb + t] = incl - v;
  if (t == 0) rowptr[mp * (N + 1) + N] = E;
}

__global__ __launch_bounds__(256) void scan_final(
    const int* __restrict__ deg, const int* __restrict__ bsum,
    int* __restrict__ rowptr, int* __restrict__ cursor, int N, int nb)
{
  int mp = blockIdx.y;
  int i = blockIdx.x * 256 + threadIdx.x;
  int v = (i < N) ? deg[mp * N + i] : 0;
  int incl = block_incl_scan(v);
  int off = bsum[mp * nb + blockIdx.x];
  if (i < N) {
    int ex = off + incl - v;
    rowptr[mp * (N + 1) + i] = ex;
    cursor[mp * N + i] = ex;
  }
}

__global__ __launch_bounds__(256) void scatter_edges(
    const int* __restrict__ i0, const float* __restrict__ v0,
    const int* __restrict__ i1, const float* __restrict__ v1,
    int* __restrict__ cursor, int* __restrict__ srcs, float* __restrict__ vals,
    int N, int E)
{
  int mp = blockIdx.y;
  const int* idx = mp ? i1 : i0;
  const float* val = mp ? v1 : v0;
  int e = blockIdx.x * 256 + threadIdx.x;
  if (e >= E) return;
  int d = idx[e], s = idx[E + e];
  int p = atomicAdd(&cursor[mp * N + d], 1);
  srcs[mp * E + p] = s;
  vals[mp * E + p] = val[e];
}

// one wave per dst node: gather + fp32 accumulate + fused bias/PReLU -> bf16
__global__ __launch_bounds__(256) void spmm_csr(
    const u16* __restrict__ fts, const int* __restrict__ rowptr,
    const int* __restrict__ srcs, const float* __restrict__ vals,
    const float* __restrict__ bias, const float* __restrict__ alpha,
    u16* __restrict__ e, int N)
{
  int gw = (int)((blockIdx.x * 256 + threadIdx.x) >> 6);
  if (gw >= N) return;
  int lane = threadIdx.x & 63;
  int beg = rowptr[gw], end = rowptr[gw + 1];
  float a0 = 0.f, a1 = 0.f, a2 = 0.f, a3 = 0.f;
  for (int base = beg; base < end; base += 64) {
    int k = base + lane;
    int sv = 0; float vv = 0.f;
    if (k < end) { sv = srcs[k]; vv = vals[k]; }
    int cnt = min(64, end - base);
    for (int j = 0; j < cnt; ++j) {
      int sj = __shfl(sv, j);
      float vj = __shfl(vv, j);
      ushort4 r = *(const ushort4*)(fts + (size_t)sj * H + lane * 4);
      a0 += vj * bf2f(r.x);
      a1 += vj * bf2f(r.y);
      a2 += vj * bf2f(r.z);
      a3 += vj * bf2f(r.w);
    }
  }
  int c = lane * 4;
  float al = alpha[0];
  float r0 = a0 + bias[c],     r1 = a1 + bias[c + 1];
  float r2 = a2 + bias[c + 2], r3 = a3 + bias[c + 3];
  r0 = r0 > 0.f ? r0 : al * r0;
  r1 = r1 > 0.f ? r1 : al * r1;
  r2 = r2 > 0.f ? r2 : al * r2;
  r3 = r3 > 0.f ? r3 : al * r3;
  *(ushort4*)(e + (size_t)gw * H + c) =
      make_ushort4(f2bf(r0), f2bf(r1), f2bf(r2), f2bf(r3));
}

// ================= GEMM (m97 structure) =======================================
// C[M,256] = A[M,256] @ W[256,256]^T   (bf16 operands, fp32 accum)
// MODE 0: store C as bf16
// MODE 1: colsum[n] += sum_m tanh(C[m][n] + bias[n])
template <int MODE>
__global__ __launch_bounds__(256) void gemm_bt(
    const u16* __restrict__ A, const u16* __restrict__ W,
    u16* __restrict__ C, const float* __restrict__ bias,
    float* __restrict__ colsum, int M)
{
  __shared__ u16 As[128 * 64];
  __shared__ u16 Bs[128 * 64];
  const int tid  = threadIdx.x;
  const int lane = tid & 63;
  const int wave = tid >> 6;
  const int quad = lane >> 4;
  const int l15  = lane & 15;
  const int m0 = blockIdx.x * 128;
  const int n0 = blockIdx.y * 128;
  const int wr = (wave & 1) * 64;
  const int wc = (wave >> 1) * 64;

  f32x4 acc[4][4] = {};

  for (int k0 = 0; k0 < H; k0 += 64) {
    #pragma unroll
    for (int r = 0; r < 4; ++r) {
      int chunk = r * 256 + tid;
      int row = chunk >> 3;
      int col = (chunk & 7) * 8;
      int gm = m0 + row; if (gm >= M) gm = M - 1;
      u16* lbase = As + (r * 256 + wave * 64) * 8;
      async16(A + gm * H + k0 + col, lbase);
      u16* lbase2 = Bs + (r * 256 + wave * 64) * 8;
      async16(W + (n0 + row) * H + k0 + col, lbase2);
    }
    __syncthreads();
    #pragma unroll
    for (int kk = 0; kk < 64; kk += 32) {
      short8 af[4], bf[4];
      #pragma unroll
      for (int i = 0; i < 4; ++i) {
        af[i] = *(const short8*)(As + (wr + i * 16 + l15) * 64 + kk + quad * 8);
        bf[i] = *(const short8*)(Bs + (wc + i * 16 + l15) * 64 + kk + quad * 8);
      }
      #pragma unroll
      for (int mi = 0; mi < 4; ++mi)
        #pragma unroll
        for (int ni = 0; ni < 4; ++ni)
          acc[mi][ni] = __builtin_amdgcn_mfma_f32_16x16x32_bf16(af[mi], bf[ni], acc[mi][ni], 0, 0, 0);
    }
    __syncthreads();
  }

  if (MODE == 0) {
    #pragma unroll
    for (int mi = 0; mi < 4; ++mi)
      #pragma unroll
      for (int ni = 0; ni < 4; ++ni) {
        int n = n0 + wc + ni * 16 + l15;
        #pragma unroll
        for (int j = 0; j < 4; ++j) {
          int m = m0 + wr + mi * 16 + quad * 4 + j;
          if (m < M) C[m * H + n] = f2bf(acc[mi][ni][j]);
        }
      }
  } else {
    #pragma unroll
    for (int ni = 0; ni < 4; ++ni) {
      int n = n0 + wc + ni * 16 + l15;
      float bv = bias[n];
      float s = 0.f;
      #pragma unroll
      for (int mi = 0; mi < 4; ++mi)
        #pragma unroll
        for (int j = 0; j < 4; ++j) {
          int m = m0 + wr + mi * 16 + quad * 4 + j;
          if (m < M) {
            float x = acc[mi][ni][j] + bv;
            s += 1.f - 2.f / (__expf(2.f * x) + 1.f);
          }
        }
      s += __shfl_xor(s, 16);
      s += __shfl_xor(s, 32);
      if (lane < 16) unsafeAtomicAdd(&colsum[n], s);
    }
  }
}

__global__ __launch_bounds__(256) void compute_beta(
    const float* __restrict__ sp, const float* __restrict__ att,
    float invN, float* __restrict__ beta)
{
  __shared__ float red0[4], red1[4];
  int t = threadIdx.x;
  float a = att[t];
  float s0 = sp[t] * invN * a;
  float s1 = sp[H + t] * invN * a;
  #pragma unroll
  for (int off = 32; off > 0; off >>= 1) {
    s0 += __shfl_down(s0, off);
    s1 += __shfl_down(s1, off);
  }
  int lane = t & 63, w = t >> 6;
  if (lane == 0) { red0[w] = s0; red1[w] = s1; }
  __syncthreads();
  if (t == 0) {
    float a0 = red0[0] + red0[1] + red0[2] + red0[3];
    float a1 = red1[0] + red1[1] + red1[2] + red1[3];
    float mx = fmaxf(a0, a1);
    float e0v = __expf(a0 - mx), e1v = __expf(a1 - mx);
    float inv = 1.f / (e0v + e1v);
    beta[0] = e0v * inv;
    beta[1] = e1v * inv;
  }
}

__global__ __launch_bounds__(256) void fuse_out(
    const u16* __restrict__ e0, const u16* __restrict__ e1,
    const float* __restrict__ beta, float* __restrict__ out, int total)
{
  int i = (blockIdx.x * 256 + threadIdx.x) * 4;
  if (i >= total) return;
  float b0 = beta[0], b1 = beta[1];
  ushort4 u0 = *(const ushort4*)(e0 + i);
  ushort4 u1 = *(const ushort4*)(e1 + i);
  float4 o;
  o.x = b0 * bf2f(u0.x) + b1 * bf2f(u1.x);
  o.y = b0 * bf2f(u0.y) + b1 * bf2f(u1.y);
  o.z = b0 * bf2f(u0.z) + b1 * bf2f(u1.z);
  o.w = b0 * bf2f(u0.w) + b1 * bf2f(u1.w);
  *(float4*)(out + i) = o;
}

extern "C" void kernel_launch(void* const* d_in, const int* in_sizes, int n_in,
                              void* d_out, int out_size, void* d_ws, size_t ws_size,
                              hipStream_t stream)
{
  const float* h_in[2] = {(const float*)d_in[0], (const float*)d_in[1]};
  const int N = in_sizes[0] / H;      // 50000
  const int E = in_sizes[3];          // 800000
  const int* idx[4]; const float* val[4];
  for (int i = 0; i < 4; ++i) {
    idx[i] = (const int*)d_in[2 + 2 * i];
    val[i] = (const float*)d_in[3 + 2 * i];
  }
  const float *W[4], *bia[4], *alp[4];
  for (int i = 0; i < 4; ++i) {
    W[i]   = (const float*)d_in[10 + 3 * i];
    bia[i] = (const float*)d_in[11 + 3 * i];
    alp[i] = (const float*)d_in[12 + 3 * i];
  }
  const float *fcW[2], *fcb[2], *att[2];
  for (int s = 0; s < 2; ++s) {
    fcW[s] = (const float*)d_in[22 + 3 * s];
    fcb[s] = (const float*)d_in[23 + 3 * s];
    att[s] = (const float*)d_in[24 + 3 * s];
  }

  const size_t NH = (size_t)N * H;
  const int nb = (N + 255) / 256;     // 196 (must be <= 256)
  auto align256 = [](size_t x) { return (x + 255) & ~(size_t)255; };
  char* p = (char*)d_ws;
  u16* fts = (u16*)p;     p += align256(NH * 2);
  u16* e0b = (u16*)p;     p += align256(NH * 2);
  u16* e1b = (u16*)p;     p += align256(NH * 2);
  u16* hbf = (u16*)p;     p += align256(NH * 2);
  u16* Wbf = (u16*)p;     p += align256((size_t)6 * H * H * 2);
  int* deg = (int*)p;     p += align256((size_t)2 * N * 4);
  int* rowptr = (int*)p;  p += align256((size_t)2 * (N + 1) * 4);
  int* cursor = (int*)p;  p += align256((size_t)2 * N * 4);
  int* bsum = (int*)p;    p += align256((size_t)2 * 256 * 4);
  int* srcs = (int*)p;    p += align256((size_t)2 * E * 4);
  float* vals = (float*)p; p += align256((size_t)2 * E * 4);
  float* sp = (float*)p;  p += align256((size_t)2 * H * 4);
  float* beta = (float*)p;

  const int gx = (N + 127) / 128;
  dim3 ggrid(gx, 2);
  const int tot = (int)NH;
  const int el_blocks = tot / 4 / 256;
  const int eb = (E + 255) / 256;
  dim3 egrid(eb, 2), ngrid(nb, 2), onegrid(1, 2);
  const int spmm_blocks = (N + 3) / 4;

  dim3 wgrid(H * H / 1024, 6);
  cvt_weights<<<wgrid, 256, 0, stream>>>(W[0], W[1], W[2], W[3], fcW[0], fcW[1], Wbf);

  for (int s = 0; s < 2; ++s) {
    float* outz = (float*)d_out + (size_t)s * NH;
    cvt_bf16<<<el_blocks, 256, 0, stream>>>(h_in[s], hbf, tot);

    // ---- CSR build for both metapaths of this side ----
    int p0 = s * 2, p1 = s * 2 + 1;
    hipMemsetAsync(deg, 0, (size_t)2 * N * 4, stream);
    hist_edges<<<egrid, 256, 0, stream>>>(idx[p0], idx[p1], deg, N, E);
    scan_partial<<<ngrid, 256, 0, stream>>>(deg, bsum, N, nb);
    scan_blocks<<<onegrid, 256, 0, stream>>>(bsum, rowptr, N, nb, E);
    scan_final<<<ngrid, 256, 0, stream>>>(deg, bsum, rowptr, cursor, N, nb);
    scatter_edges<<<egrid, 256, 0, stream>>>(idx[p0], val[p0], idx[p1], val[p1],
                                             cursor, srcs, vals, N, E);

    for (int m = 0; m < 2; ++m) {
      int pi = s * 2 + m;
      gemm_bt<0><<<ggrid, 256, 0, stream>>>(hbf, Wbf + (size_t)pi * H * H, fts,
                                            nullptr, nullptr, N);
      spmm_csr<<<spmm_blocks, 256, 0, stream>>>(
          fts, rowptr + (size_t)m * (N + 1), srcs + (size_t)m * E,
          vals + (size_t)m * E, bia[pi], alp[pi], m == 0 ? e0b : e1b, N);
    }
    hipMemsetAsync(sp, 0, 2 * H * 4, stream);
    gemm_bt<1><<<ggrid, 256, 0, stream>>>(e0b, Wbf + (size_t)(4 + s) * H * H,
                                          nullptr, fcb[s], sp, N);
    gemm_bt<1><<<ggrid, 256, 0, stream>>>(e1b, Wbf + (size_t)(4 + s) * H * H,
                                          nullptr, fcb[s], sp + H, N);
    compute_beta<<<1, 256, 0, stream>>>(sp, att[s], 1.0f / (float)N, beta);
    fuse_out<<<el_blocks, 256, 0, stream>>>(e0b, e1b, beta, outz, tot);
  }
}

// Round 4
// 1101.935 us; speedup vs baseline: 10.1025x; 1.0290x over previous
//
#include <hip/hip_runtime.h>
#include <cstdint>

#define H 256

typedef unsigned short u16;
typedef __attribute__((ext_vector_type(8))) short short8;
typedef __attribute__((ext_vector_type(4))) float f32x4;

__device__ __forceinline__ float bf2f(u16 u) {
  return __uint_as_float(((unsigned)u) << 16);
}
__device__ __forceinline__ u16 f2bf(float f) {
  unsigned u = __float_as_uint(f);
  u = (u + 0x7FFF + ((u >> 16) & 1)) >> 16;   // RNE
  return (u16)u;
}
__device__ __forceinline__ void async16(const void* g, void* l) {
  __builtin_amdgcn_global_load_lds((const __attribute__((address_space(1))) void*)g,
                                   (__attribute__((address_space(3))) void*)l, 16, 0, 0);
}

// ---- fp32 -> bf16 converters ----
__global__ __launch_bounds__(256) void cvt_bf16(
    const float* __restrict__ src, u16* __restrict__ dst, int total)
{
  int i = (blockIdx.x * 256 + threadIdx.x) * 4;
  if (i >= total) return;
  float4 x = *(const float4*)(src + i);
  *(ushort4*)(dst + i) = make_ushort4(f2bf(x.x), f2bf(x.y), f2bf(x.z), f2bf(x.w));
}

__global__ __launch_bounds__(256) void cvt_weights(
    const float* w0, const float* w1, const float* w2, const float* w3,
    const float* w4, const float* w5, u16* __restrict__ dst)
{
  const float* srcs[6] = {w0, w1, w2, w3, w4, w5};
  const float* s = srcs[blockIdx.y];
  int i = (blockIdx.x * 256 + threadIdx.x) * 4;
  float4 x = *(const float4*)(s + i);
  *(ushort4*)(dst + blockIdx.y * (H * H) + i) =
      make_ushort4(f2bf(x.x), f2bf(x.y), f2bf(x.z), f2bf(x.w));
}

// ============ CSR build, batched over ALL 4 metapaths via blockIdx.y ==========

__global__ __launch_bounds__(256) void hist_edges(
    const int* i0, const int* i1, const int* i2, const int* i3,
    int* __restrict__ deg, int N, int E)
{
  int mp = blockIdx.y;
  const int* idxs[4] = {i0, i1, i2, i3};
  const int* idx = idxs[mp];
  int e = blockIdx.x * 256 + threadIdx.x;
  if (e < E) atomicAdd(&deg[mp * N + idx[e]], 1);
}

__device__ __forceinline__ int block_incl_scan(int v) {
  __shared__ int wsum[4];
  int tid = threadIdx.x, lane = tid & 63, w = tid >> 6;
  int x = v;
  #pragma unroll
  for (int off = 1; off < 64; off <<= 1) {
    int n = __shfl_up(x, off);
    if (lane >= off) x += n;
  }
  if (lane == 63) wsum[w] = x;
  __syncthreads();
  int add = 0;
  #pragma unroll
  for (int i = 0; i < 4; ++i) add += (i < w) ? wsum[i] : 0;
  return x + add;
}

__global__ __launch_bounds__(256) void scan_partial(
    const int* __restrict__ deg, int* __restrict__ bsum, int N, int nb)
{
  int mp = blockIdx.y;
  int i = blockIdx.x * 256 + threadIdx.x;
  int v = (i < N) ? deg[mp * N + i] : 0;
  #pragma unroll
  for (int off = 32; off; off >>= 1) v += __shfl_down(v, off);
  __shared__ int ws2[4];
  int lane = threadIdx.x & 63, w = threadIdx.x >> 6;
  if (lane == 0) ws2[w] = v;
  __syncthreads();
  if (threadIdx.x == 0)
    bsum[mp * nb + blockIdx.x] = ws2[0] + ws2[1] + ws2[2] + ws2[3];
}

// nb <= 256 required (N<=65536)
__global__ __launch_bounds__(256) void scan_blocks(
    int* __restrict__ bsum, int* __restrict__ rowptr, int N, int nb, int E)
{
  int mp = blockIdx.y;
  int t = threadIdx.x;
  int v = (t < nb) ? bsum[mp * nb + t] : 0;
  int incl = block_incl_scan(v);
  if (t < nb) bsum[mp * nb + t] = incl - v;
  if (t == 0) rowptr[mp * (N + 1) + N] = E;
}

__global__ __launch_bounds__(256) void scan_final(
    const int* __restrict__ deg, const int* __restrict__ bsum,
    int* __restrict__ rowptr, int* __restrict__ cursor, int N, int nb)
{
  int mp = blockIdx.y;
  int i = blockIdx.x * 256 + threadIdx.x;
  int v = (i < N) ? deg[mp * N + i] : 0;
  int incl = block_incl_scan(v);
  int off = bsum[mp * nb + blockIdx.x];
  if (i < N) {
    int ex = off + incl - v;
    rowptr[mp * (N + 1) + i] = ex;
    cursor[mp * N + i] = ex;
  }
}

// single 8B scatter per edge: {src, val_bits}
__global__ __launch_bounds__(256) void scatter_edges(
    const int* i0, const int* i1, const int* i2, const int* i3,
    const float* v0, const float* v1, const float* v2, const float* v3,
    int* __restrict__ cursor, int2* __restrict__ edges, int N, int E)
{
  int mp = blockIdx.y;
  const int* idxs[4] = {i0, i1, i2, i3};
  const float* valp[4] = {v0, v1, v2, v3};
  const int* idx = idxs[mp];
  int e = blockIdx.x * 256 + threadIdx.x;
  if (e >= E) return;
  int d = idx[e], s = idx[E + e];
  float v = valp[mp][e];
  int p = atomicAdd(&cursor[mp * N + d], 1);
  edges[(size_t)mp * E + p] = make_int2(s, __float_as_int(v));
}

// one wave per dst node: gather + fp32 accumulate + fused bias/PReLU -> bf16
// 4x-unrolled gather: 4 independent row loads in flight
__global__ __launch_bounds__(256) void spmm_csr(
    const u16* __restrict__ fts, const int* __restrict__ rowptr,
    const int2* __restrict__ edges, const float* __restrict__ bias,
    const float* __restrict__ alpha, u16* __restrict__ e, int N)
{
  int gw = (int)((blockIdx.x * 256 + threadIdx.x) >> 6);
  if (gw >= N) return;
  int lane = threadIdx.x & 63;
  int beg = rowptr[gw], end = rowptr[gw + 1];
  float a0 = 0.f, a1 = 0.f, a2 = 0.f, a3 = 0.f;
  for (int base = beg; base < end; base += 64) {
    int k = base + lane;
    int2 ev = make_int2(0, 0);
    if (k < end) ev = edges[k];
    int cnt = min(64, end - base);
    int j = 0;
    for (; j + 4 <= cnt; j += 4) {
      int sj[4]; float vj[4]; ushort4 r[4];
      #pragma unroll
      for (int u = 0; u < 4; ++u) {
        sj[u] = __shfl(ev.x, j + u);
        vj[u] = __uint_as_float((unsigned)__shfl(ev.y, j + u));
      }
      #pragma unroll
      for (int u = 0; u < 4; ++u)
        r[u] = *(const ushort4*)(fts + (size_t)sj[u] * H + lane * 4);
      #pragma unroll
      for (int u = 0; u < 4; ++u) {
        a0 += vj[u] * bf2f(r[u].x);
        a1 += vj[u] * bf2f(r[u].y);
        a2 += vj[u] * bf2f(r[u].z);
        a3 += vj[u] * bf2f(r[u].w);
      }
    }
    for (; j < cnt; ++j) {
      int sj = __shfl(ev.x, j);
      float vj = __uint_as_float((unsigned)__shfl(ev.y, j));
      ushort4 r = *(const ushort4*)(fts + (size_t)sj * H + lane * 4);
      a0 += vj * bf2f(r.x);
      a1 += vj * bf2f(r.y);
      a2 += vj * bf2f(r.z);
      a3 += vj * bf2f(r.w);
    }
  }
  int c = lane * 4;
  float al = alpha[0];
  float r0 = a0 + bias[c],     r1 = a1 + bias[c + 1];
  float r2 = a2 + bias[c + 2], r3 = a3 + bias[c + 3];
  r0 = r0 > 0.f ? r0 : al * r0;
  r1 = r1 > 0.f ? r1 : al * r1;
  r2 = r2 > 0.f ? r2 : al * r2;
  r3 = r3 > 0.f ? r3 : al * r3;
  *(ushort4*)(e + (size_t)gw * H + c) =
      make_ushort4(f2bf(r0), f2bf(r1), f2bf(r2), f2bf(r3));
}

// ================= GEMM (m97 structure) =======================================
template <int MODE>
__global__ __launch_bounds__(256) void gemm_bt(
    const u16* __restrict__ A, const u16* __restrict__ W,
    u16* __restrict__ C, const float* __restrict__ bias,
    float* __restrict__ colsum, int M)
{
  __shared__ u16 As[128 * 64];
  __shared__ u16 Bs[128 * 64];
  const int tid  = threadIdx.x;
  const int lane = tid & 63;
  const int wave = tid >> 6;
  const int quad = lane >> 4;
  const int l15  = lane & 15;
  const int m0 = blockIdx.x * 128;
  const int n0 = blockIdx.y * 128;
  const int wr = (wave & 1) * 64;
  const int wc = (wave >> 1) * 64;

  f32x4 acc[4][4] = {};

  for (int k0 = 0; k0 < H; k0 += 64) {
    #pragma unroll
    for (int r = 0; r < 4; ++r) {
      int chunk = r * 256 + tid;
      int row = chunk >> 3;
      int col = (chunk & 7) * 8;
      int gm = m0 + row; if (gm >= M) gm = M - 1;
      u16* lbase = As + (r * 256 + wave * 64) * 8;
      async16(A + gm * H + k0 + col, lbase);
      u16* lbase2 = Bs + (r * 256 + wave * 64) * 8;
      async16(W + (n0 + row) * H + k0 + col, lbase2);
    }
    __syncthreads();
    #pragma unroll
    for (int kk = 0; kk < 64; kk += 32) {
      short8 af[4], bf[4];
      #pragma unroll
      for (int i = 0; i < 4; ++i) {
        af[i] = *(const short8*)(As + (wr + i * 16 + l15) * 64 + kk + quad * 8);
        bf[i] = *(const short8*)(Bs + (wc + i * 16 + l15) * 64 + kk + quad * 8);
      }
      #pragma unroll
      for (int mi = 0; mi < 4; ++mi)
        #pragma unroll
        for (int ni = 0; ni < 4; ++ni)
          acc[mi][ni] = __builtin_amdgcn_mfma_f32_16x16x32_bf16(af[mi], bf[ni], acc[mi][ni], 0, 0, 0);
    }
    __syncthreads();
  }

  if (MODE == 0) {
    #pragma unroll
    for (int mi = 0; mi < 4; ++mi)
      #pragma unroll
      for (int ni = 0; ni < 4; ++ni) {
        int n = n0 + wc + ni * 16 + l15;
        #pragma unroll
        for (int j = 0; j < 4; ++j) {
          int m = m0 + wr + mi * 16 + quad * 4 + j;
          if (m < M) C[m * H + n] = f2bf(acc[mi][ni][j]);
        }
      }
  } else {
    #pragma unroll
    for (int ni = 0; ni < 4; ++ni) {
      int n = n0 + wc + ni * 16 + l15;
      float bv = bias[n];
      float s = 0.f;
      #pragma unroll
      for (int mi = 0; mi < 4; ++mi)
        #pragma unroll
        for (int j = 0; j < 4; ++j) {
          int m = m0 + wr + mi * 16 + quad * 4 + j;
          if (m < M) {
            float x = acc[mi][ni][j] + bv;
            s += 1.f - 2.f / (__expf(2.f * x) + 1.f);
          }
        }
      s += __shfl_xor(s, 16);
      s += __shfl_xor(s, 32);
      if (lane < 16) unsafeAtomicAdd(&colsum[n], s);
    }
  }
}

__global__ __launch_bounds__(256) void compute_beta(
    const float* __restrict__ sp, const float* __restrict__ att,
    float invN, float* __restrict__ beta)
{
  __shared__ float red0[4], red1[4];
  int t = threadIdx.x;
  float a = att[t];
  float s0 = sp[t] * invN * a;
  float s1 = sp[H + t] * invN * a;
  #pragma unroll
  for (int off = 32; off > 0; off >>= 1) {
    s0 += __shfl_down(s0, off);
    s1 += __shfl_down(s1, off);
  }
  int lane = t & 63, w = t >> 6;
  if (lane == 0) { red0[w] = s0; red1[w] = s1; }
  __syncthreads();
  if (t == 0) {
    float a0 = red0[0] + red0[1] + red0[2] + red0[3];
    float a1 = red1[0] + red1[1] + red1[2] + red1[3];
    float mx = fmaxf(a0, a1);
    float e0v = __expf(a0 - mx), e1v = __expf(a1 - mx);
    float inv = 1.f / (e0v + e1v);
    beta[0] = e0v * inv;
    beta[1] = e1v * inv;
  }
}

__global__ __launch_bounds__(256) void fuse_out(
    const u16* __restrict__ e0, const u16* __restrict__ e1,
    const float* __restrict__ beta, float* __restrict__ out, int total)
{
  int i = (blockIdx.x * 256 + threadIdx.x) * 4;
  if (i >= total) return;
  float b0 = beta[0], b1 = beta[1];
  ushort4 u0 = *(const ushort4*)(e0 + i);
  ushort4 u1 = *(const ushort4*)(e1 + i);
  float4 o;
  o.x = b0 * bf2f(u0.x) + b1 * bf2f(u1.x);
  o.y = b0 * bf2f(u0.y) + b1 * bf2f(u1.y);
  o.z = b0 * bf2f(u0.z) + b1 * bf2f(u1.z);
  o.w = b0 * bf2f(u0.w) + b1 * bf2f(u1.w);
  *(float4*)(out + i) = o;
}

extern "C" void kernel_launch(void* const* d_in, const int* in_sizes, int n_in,
                              void* d_out, int out_size, void* d_ws, size_t ws_size,
                              hipStream_t stream)
{
  const float* h_in[2] = {(const float*)d_in[0], (const float*)d_in[1]};
  const int N = in_sizes[0] / H;      // 50000
  const int E = in_sizes[3];          // 800000
  const int* idx[4]; const float* val[4];
  for (int i = 0; i < 4; ++i) {
    idx[i] = (const int*)d_in[2 + 2 * i];
    val[i] = (const float*)d_in[3 + 2 * i];
  }
  const float *W[4], *bia[4], *alp[4];
  for (int i = 0; i < 4; ++i) {
    W[i]   = (const float*)d_in[10 + 3 * i];
    bia[i] = (const float*)d_in[11 + 3 * i];
    alp[i] = (const float*)d_in[12 + 3 * i];
  }
  const float *fcW[2], *fcb[2], *att[2];
  for (int s = 0; s < 2; ++s) {
    fcW[s] = (const float*)d_in[22 + 3 * s];
    fcb[s] = (const float*)d_in[23 + 3 * s];
    att[s] = (const float*)d_in[24 + 3 * s];
  }

  const size_t NH = (size_t)N * H;
  const int nb = (N + 255) / 256;     // 196 (must be <= 256)
  auto align256 = [](size_t x) { return (x + 255) & ~(size_t)255; };
  char* p = (char*)d_ws;
  u16* fts = (u16*)p;      p += align256(NH * 2);            // 25.6 MB
  u16* e0b = (u16*)p;      p += align256(NH * 2);            // 25.6 MB
  u16* hbf = (u16*)p;      p += align256(NH * 2);            // 25.6 MB (aliases e1b)
  u16* Wbf = (u16*)p;      p += align256((size_t)6 * H * H * 2);
  int* deg = (int*)p;      p += align256((size_t)4 * N * 4);
  int* rowptr = (int*)p;   p += align256((size_t)4 * (N + 1) * 4);
  int* cursor = (int*)p;   p += align256((size_t)4 * N * 4);
  int* bsum = (int*)p;     p += align256((size_t)4 * 256 * 4);
  int2* edges = (int2*)p;  p += align256((size_t)4 * E * 8); // 25.6 MB
  float* sp = (float*)p;   p += align256((size_t)2 * H * 4);
  float* beta = (float*)p;
  u16* e1b = hbf;          // hbf dead after 2nd MODE-0 GEMM of each side

  const int gx = (N + 127) / 128;
  dim3 ggrid(gx, 2);
  const int tot = (int)NH;
  const int el_blocks = tot / 4 / 256;
  const int eb = (E + 255) / 256;
  dim3 egrid(eb, 4), ngrid(nb, 4), onegrid(1, 4);
  const int spmm_blocks = (N + 3) / 4;

  dim3 wgrid(H * H / 1024, 6);
  cvt_weights<<<wgrid, 256, 0, stream>>>(W[0], W[1], W[2], W[3], fcW[0], fcW[1], Wbf);

  // ---- CSR build for all 4 metapaths, once ----
  hipMemsetAsync(deg, 0, (size_t)4 * N * 4, stream);
  hist_edges<<<egrid, 256, 0, stream>>>(idx[0], idx[1], idx[2], idx[3], deg, N, E);
  scan_partial<<<ngrid, 256, 0, stream>>>(deg, bsum, N, nb);
  scan_blocks<<<onegrid, 256, 0, stream>>>(bsum, rowptr, N, nb, E);
  scan_final<<<ngrid, 256, 0, stream>>>(deg, bsum, rowptr, cursor, N, nb);
  scatter_edges<<<egrid, 256, 0, stream>>>(idx[0], idx[1], idx[2], idx[3],
                                           val[0], val[1], val[2], val[3],
                                           cursor, edges, N, E);

  for (int s = 0; s < 2; ++s) {
    float* outz = (float*)d_out + (size_t)s * NH;
    cvt_bf16<<<el_blocks, 256, 0, stream>>>(h_in[s], hbf, tot);

    for (int m = 0; m < 2; ++m) {
      int pi = s * 2 + m;
      gemm_bt<0><<<ggrid, 256, 0, stream>>>(hbf, Wbf + (size_t)pi * H * H, fts,
                                            nullptr, nullptr, N);
      spmm_csr<<<spmm_blocks, 256, 0, stream>>>(
          fts, rowptr + (size_t)pi * (N + 1), edges + (size_t)pi * E,
          bia[pi], alp[pi], m == 0 ? e0b : e1b, N);
    }
    hipMemsetAsync(sp, 0, 2 * H * 4, stream);
    gemm_bt<1><<<ggrid, 256, 0, stream>>>(e0b, Wbf + (size_t)(4 + s) * H * H,
                                          nullptr, fcb[s], sp, N);
    gemm_bt<1><<<ggrid, 256, 0, stream>>>(e1b, Wbf + (size_t)(4 + s) * H * H,
                                          nullptr, fcb[s], sp + H, N);
    compute_beta<<<1, 256, 0, stream>>>(sp, att[s], 1.0f / (float)N, beta);
    fuse_out<<<el_blocks, 256, 0, stream>>>(e0b, e1b, beta, outz, tot);
  }
}